// Round 2
// baseline (391.337 us; speedup 1.0000x reference)
//
#include <hip/hip_runtime.h>

// KroneckerAttention on MI355X (gfx950).
// B=2,H=16 (BH=32), N=4096, D=128, m=n=4 -> p=q=1024, c0=c1=2, k_picked=0.
//
// Pipeline (all on `stream`):
//  K0a: Kc  f16 [bh][1024][128]   = key[bh][2048+r][:]            (convert)
//  K0b: VT  f16 [bh][g][128][1024]= value[bh][g*1024+k][d]        (transpose+convert)
//  K1 : norms2[bh][qi][g] = sum_pi (Q[bh][qi*1024+pi] . K[bh][g*1024])^2  (atomics)
//  K1b: wts[bh][qi][g] = n/Sum_g n ; logS[bh][qi] = log(Sum_g n) - log(n[2][2])
//  K2a: lse0[bh][1024] = logsumexp_j(scale * Qc.Kc^T)  (MFMA, online max/sum)
//  K2b: main: per (bh, 64-row qtile): S=Qc.Kc^T, P=exp(S*scale-lse0),
//       acc_g += P.V_g (wave pairs per group), epilogue: out[qi] = sum_g wts*acc_g,
//       lse[qi*1024+pi] = lse0[pi] + logS[qi].
// MFMA frag maps (guide-verified): A/B: lane&15 = row/col, 8 contiguous K elems
// per lane (any within-window K permutation cancels between A and B);
// C/D: col=lane&15, row=(lane>>4)*4+reg.

typedef _Float16 f16x8 __attribute__((ext_vector_type(8)));
typedef _Float16 f16x4 __attribute__((ext_vector_type(4)));
typedef float    f32x4 __attribute__((ext_vector_type(4)));

#define SCALE 0.08838834764831845f

__device__ __forceinline__ int xcd_swz(int wg, int nwg) {
  int chunk = nwg >> 3;  // nwg % 8 == 0 (bijective)
  return (wg & 7) * chunk + (wg >> 3);
}

// ---------------- K0a: Kc build (convert center K rows to f16) --------------
__global__ __launch_bounds__(256) void k_build_kc(const float* __restrict__ k,
                                                  _Float16* __restrict__ Kc) {
  int idx = blockIdx.x * 256 + threadIdx.x;      // 1,048,576 float4s
  int bh  = idx >> 15;                           // 32768 float4 per bh
  int rem = idx & 32767;
  int r   = rem >> 5, c4 = rem & 31;
  float4 v = *(const float4*)(k + ((size_t)bh * 4096 + 2048 + r) * 128 + c4 * 4);
  f16x4 o = {(_Float16)v.x, (_Float16)v.y, (_Float16)v.z, (_Float16)v.w};
  *(f16x4*)(Kc + ((size_t)bh * 1024 + r) * 128 + c4 * 4) = o;
}

// ---------------- K0b: VT build (transpose V per group, f16) ----------------
__global__ __launch_bounds__(256) void k_build_vt(const float* __restrict__ v,
                                                  _Float16* __restrict__ VT) {
  __shared__ _Float16 tile[128 * 136];           // [k 128][d 128+8pad]
  int blk = blockIdx.x;                          // 32 bh * 4 g * 8 ktile
  int bh = blk >> 5, g = (blk >> 3) & 3, kt = blk & 7;
  int t = threadIdx.x;
  const float* src = v + ((size_t)bh * 4096 + g * 1024 + kt * 128) * 128;
#pragma unroll
  for (int i = 0; i < 16; ++i) {
    int idx = i * 256 + t;
    int r = idx >> 5, c4 = idx & 31;
    float4 vv = *(const float4*)(src + (size_t)r * 128 + c4 * 4);
    f16x4 o = {(_Float16)vv.x, (_Float16)vv.y, (_Float16)vv.z, (_Float16)vv.w};
    *(f16x4*)&tile[r * 136 + c4 * 4] = o;
  }
  __syncthreads();
  _Float16* dst = VT + (size_t)(bh * 4 + g) * 128 * 1024 + kt * 128;
#pragma unroll
  for (int i = 0; i < 16; ++i) {
    int idx = i * 256 + t;
    int dd = idx >> 5, k4 = idx & 31;
    f16x4 o = {tile[(k4 * 4 + 0) * 136 + dd], tile[(k4 * 4 + 1) * 136 + dd],
               tile[(k4 * 4 + 2) * 136 + dd], tile[(k4 * 4 + 3) * 136 + dd]};
    *(f16x4*)(dst + (size_t)dd * 1024 + k4 * 4) = o;
  }
}

// ---------------- K1: norms2 via sampled-key dots ---------------------------
__global__ __launch_bounds__(256) void k_norms(const float* __restrict__ q,
                                               const float* __restrict__ k,
                                               float* __restrict__ norms2) {
  __shared__ float ks[4][128];
  int b = blockIdx.x;                            // 512 = 32 bh * 4 qi * 4 slices
  int bh = b >> 4, qi = (b >> 2) & 3, sl = b & 3;
  int t = threadIdx.x;
  for (int i = t; i < 512; i += 256)
    ks[i >> 7][i & 127] = k[((size_t)bh * 4096 + (i >> 7) * 1024) * 128 + (i & 127)];
  __syncthreads();
  int w = t >> 6, lane = t & 63, l15 = lane & 15, l4 = lane >> 4;
  float ksr[4][8];
#pragma unroll
  for (int gg = 0; gg < 4; ++gg)
#pragma unroll
    for (int j = 0; j < 8; ++j) ksr[gg][j] = ks[gg][l15 * 8 + j];
  float n2[4] = {0.f, 0.f, 0.f, 0.f};
  const float* qb = q + ((size_t)bh * 4096 + qi * 1024 + sl * 256) * 128;
  for (int it = 0; it < 16; ++it) {
    int row = it * 16 + w * 4 + l4;
    const float* qr = qb + (size_t)row * 128 + l15 * 8;
    float4 qa = *(const float4*)qr;
    float4 qc = *(const float4*)(qr + 4);
#pragma unroll
    for (int gg = 0; gg < 4; ++gg) {
      float p = qa.x * ksr[gg][0] + qa.y * ksr[gg][1] + qa.z * ksr[gg][2] +
                qa.w * ksr[gg][3] + qc.x * ksr[gg][4] + qc.y * ksr[gg][5] +
                qc.z * ksr[gg][6] + qc.w * ksr[gg][7];
      p += __shfl_xor(p, 1); p += __shfl_xor(p, 2);
      p += __shfl_xor(p, 4); p += __shfl_xor(p, 8);
      if (l15 == 0) n2[gg] += p * p;
    }
  }
  if (l15 == 0) {
#pragma unroll
    for (int gg = 0; gg < 4; ++gg)
      atomicAdd(&norms2[bh * 16 + qi * 4 + gg], n2[gg]);
  }
}

// ---------------- K1b: wts + logS -------------------------------------------
__global__ void k_wts(const float* __restrict__ norms2, float* __restrict__ wts,
                      float* __restrict__ logS) {
  int t = threadIdx.x;
  if (t < 128) {
    int bh = t >> 2, qi = t & 3;
    float n0 = sqrtf(norms2[bh * 16 + qi * 4 + 0]);
    float n1 = sqrtf(norms2[bh * 16 + qi * 4 + 1]);
    float n2v = sqrtf(norms2[bh * 16 + qi * 4 + 2]);
    float n3 = sqrtf(norms2[bh * 16 + qi * 4 + 3]);
    float S = n0 + n1 + n2v + n3;
    float nc = sqrtf(norms2[bh * 16 + 2 * 4 + 2]);
    float inv = 1.f / S;
    wts[bh * 16 + qi * 4 + 0] = n0 * inv;
    wts[bh * 16 + qi * 4 + 1] = n1 * inv;
    wts[bh * 16 + qi * 4 + 2] = n2v * inv;
    wts[bh * 16 + qi * 4 + 3] = n3 * inv;
    logS[bh * 4 + qi] = __logf(S) - __logf(nc);
  }
}

// ---------------- K2a: lse0 (MFMA online logsumexp) -------------------------
__global__ __launch_bounds__(512, 4) void k_lse0(const float* __restrict__ q,
                                                 const _Float16* __restrict__ Kc,
                                                 float* __restrict__ lse0) {
  __shared__ _Float16 Qt[128 * 136];
  __shared__ _Float16 Kt[64 * 136];
  int wg = xcd_swz(blockIdx.x, 256);
  int bh = wg >> 3;
  int q0 = (wg & 7) << 7;                        // 128-row tiles
  int t = threadIdx.x;
  int w = t >> 6, lane = t & 63, l15 = lane & 15, l4 = lane >> 4;
  const float* qbase = q + ((size_t)bh * 4096 + 2048 + q0) * 128;
#pragma unroll
  for (int i = 0; i < 8; ++i) {
    int idx = i * 512 + t;
    int r = idx >> 5, c4 = idx & 31;
    float4 vv = *(const float4*)(qbase + (size_t)r * 128 + c4 * 4);
    f16x4 o = {(_Float16)vv.x, (_Float16)vv.y, (_Float16)vv.z, (_Float16)vv.w};
    *(f16x4*)&Qt[r * 136 + c4 * 4] = o;
  }
  float m[4] = {-1e30f, -1e30f, -1e30f, -1e30f};
  float lsum[4] = {0.f, 0.f, 0.f, 0.f};
  const _Float16* kc_b = Kc + (size_t)bh * 1024 * 128;
  for (int kt = 0; kt < 16; ++kt) {
    __syncthreads();
#pragma unroll
    for (int i = 0; i < 2; ++i) {
      int idx = i * 512 + t;
      int r = idx >> 4, c8 = idx & 15;
      *(uint4*)&Kt[r * 136 + c8 * 8] =
          *(const uint4*)(kc_b + ((size_t)kt * 64 + r) * 128 + c8 * 8);
    }
    __syncthreads();
    f32x4 z = {0.f, 0.f, 0.f, 0.f};
    f32x4 sv0 = z, sv1 = z, sv2 = z, sv3 = z;
#pragma unroll
    for (int ks = 0; ks < 4; ++ks) {
      f16x8 a  = *(const f16x8*)&Qt[(w * 16 + l15) * 136 + ks * 32 + l4 * 8];
      f16x8 b0 = *(const f16x8*)&Kt[(0 + l15) * 136 + ks * 32 + l4 * 8];
      f16x8 b1 = *(const f16x8*)&Kt[(16 + l15) * 136 + ks * 32 + l4 * 8];
      f16x8 b2 = *(const f16x8*)&Kt[(32 + l15) * 136 + ks * 32 + l4 * 8];
      f16x8 b3 = *(const f16x8*)&Kt[(48 + l15) * 136 + ks * 32 + l4 * 8];
      sv0 = __builtin_amdgcn_mfma_f32_16x16x32_f16(a, b0, sv0, 0, 0, 0);
      sv1 = __builtin_amdgcn_mfma_f32_16x16x32_f16(a, b1, sv1, 0, 0, 0);
      sv2 = __builtin_amdgcn_mfma_f32_16x16x32_f16(a, b2, sv2, 0, 0, 0);
      sv3 = __builtin_amdgcn_mfma_f32_16x16x32_f16(a, b3, sv3, 0, 0, 0);
    }
#pragma unroll
    for (int r = 0; r < 4; ++r) {
      float v0 = sv0[r] * SCALE, v1 = sv1[r] * SCALE;
      float v2 = sv2[r] * SCALE, v3 = sv3[r] * SCALE;
      float vm = fmaxf(fmaxf(v0, v1), fmaxf(v2, v3));
      vm = fmaxf(vm, __shfl_xor(vm, 1));
      vm = fmaxf(vm, __shfl_xor(vm, 2));
      vm = fmaxf(vm, __shfl_xor(vm, 4));
      vm = fmaxf(vm, __shfl_xor(vm, 8));
      float mn = fmaxf(m[r], vm);
      float ps = __expf(v0 - mn) + __expf(v1 - mn) + __expf(v2 - mn) + __expf(v3 - mn);
      ps += __shfl_xor(ps, 1); ps += __shfl_xor(ps, 2);
      ps += __shfl_xor(ps, 4); ps += __shfl_xor(ps, 8);
      lsum[r] = lsum[r] * __expf(m[r] - mn) + ps;
      m[r] = mn;
    }
  }
  if (l15 == 0) {
#pragma unroll
    for (int r = 0; r < 4; ++r) {
      int row = w * 16 + l4 * 4 + r;
      lse0[bh * 1024 + q0 + row] = m[r] + __logf(lsum[r]);
    }
  }
}

// ---------------- K2b: main fused kernel ------------------------------------
// 512 threads (8 waves). Wave w: group g=w>>1, d-half dh=w&1 for PV;
// S-phase: rows (w&3)*16, cols (w>>2)*32.
#define SMEM_MAIN 118080
__global__ __launch_bounds__(512, 2) void k_main(
    const float* __restrict__ q, const _Float16* __restrict__ Kc,
    const _Float16* __restrict__ VT, const float* __restrict__ lse0,
    const float* __restrict__ wtsg, const float* __restrict__ logSg,
    float* __restrict__ out) {
  extern __shared__ char smem[];
  _Float16* Qt = (_Float16*)smem;                 // [64][136]   17408 B
  _Float16* Kt = (_Float16*)(smem + 17408);       // [64][136]   17408 B
  _Float16* Pt = (_Float16*)(smem + 34816);       // [64][72]     9216 B
  _Float16* Vt = (_Float16*)(smem + 44032);       // [4][128][72] 73728 B
  float* lse_t = (float*)(smem + 117760);         // [64]
  float* wts_t = (float*)(smem + 118016);         // [16]
  float* Ag    = (float*)(smem + 44032);          // epilogue overlay [2][64][128]

  int wg = xcd_swz(blockIdx.x, 512);
  int bh = wg >> 4;
  int q0 = (wg & 15) << 6;                        // 64-row tiles
  int t = threadIdx.x;
  int w = t >> 6, lane = t & 63, l15 = lane & 15, l4 = lane >> 4;
  int g = w >> 1, dh = w & 1;
  int sr0 = (w & 3) * 16, sc0 = (w >> 2) * 32;

  const float* qbase = q + ((size_t)bh * 4096 + 2048 + q0) * 128;
#pragma unroll
  for (int i = 0; i < 4; ++i) {
    int idx = i * 512 + t;
    int r = idx >> 5, c4 = idx & 31;
    float4 vv = *(const float4*)(qbase + (size_t)r * 128 + c4 * 4);
    f16x4 o = {(_Float16)vv.x, (_Float16)vv.y, (_Float16)vv.z, (_Float16)vv.w};
    *(f16x4*)&Qt[r * 136 + c4 * 4] = o;
  }
  if (t < 64) lse_t[t] = lse0[bh * 1024 + q0 + t];
  if (t < 16) wts_t[t] = wtsg[bh * 16 + t];

  f32x4 z = {0.f, 0.f, 0.f, 0.f};
  f32x4 acc[4][4];
#pragma unroll
  for (int i = 0; i < 4; ++i)
#pragma unroll
    for (int j = 0; j < 4; ++j) acc[i][j] = z;

  const _Float16* kc_b = Kc + (size_t)bh * 1024 * 128;
  const _Float16* vt_b = VT + (size_t)bh * 4 * 128 * 1024;

  for (int kt = 0; kt < 16; ++kt) {
    __syncthreads();  // B1: prev-iter consumers done
#pragma unroll
    for (int i = 0; i < 2; ++i) {
      int idx = i * 512 + t;
      int r = idx >> 4, c8 = idx & 15;
      *(uint4*)&Kt[r * 136 + c8 * 8] =
          *(const uint4*)(kc_b + ((size_t)kt * 64 + r) * 128 + c8 * 8);
    }
#pragma unroll
    for (int i = 0; i < 8; ++i) {
      int idx = i * 512 + t;
      int row = idx >> 3, c8 = idx & 7;           // row = g*128 + d
      *(uint4*)&Vt[row * 72 + c8 * 8] =
          *(const uint4*)(vt_b + (size_t)row * 1024 + kt * 64 + c8 * 8);
    }
    __syncthreads();  // B2: tiles staged
    // ---- S = Qc . Kc^T (this wave's 16x32 chunk) ----
    f32x4 sv0 = z, sv1 = z;
#pragma unroll
    for (int ks = 0; ks < 4; ++ks) {
      f16x8 a  = *(const f16x8*)&Qt[(sr0 + l15) * 136 + ks * 32 + l4 * 8];
      f16x8 b0 = *(const f16x8*)&Kt[(sc0 + l15) * 136 + ks * 32 + l4 * 8];
      f16x8 b1 = *(const f16x8*)&Kt[(sc0 + 16 + l15) * 136 + ks * 32 + l4 * 8];
      sv0 = __builtin_amdgcn_mfma_f32_16x16x32_f16(a, b0, sv0, 0, 0, 0);
      sv1 = __builtin_amdgcn_mfma_f32_16x16x32_f16(a, b1, sv1, 0, 0, 0);
    }
    // ---- P = exp(S*scale - lse0) -> Pt ----
#pragma unroll
    for (int r = 0; r < 4; ++r) {
      int row = sr0 + l4 * 4 + r;
      float ls = lse_t[row];
      Pt[row * 72 + sc0 + l15]      = (_Float16)__expf(sv0[r] * SCALE - ls);
      Pt[row * 72 + sc0 + 16 + l15] = (_Float16)__expf(sv1[r] * SCALE - ls);
    }
    __syncthreads();  // B3: P complete
    // ---- acc += P . V_g  (this wave: group g, d-half dh) ----
#pragma unroll
    for (int ks = 0; ks < 2; ++ks) {
      f16x8 bf[4];
#pragma unroll
      for (int ct = 0; ct < 4; ++ct)
        bf[ct] = *(const f16x8*)&Vt[(g * 128 + dh * 64 + ct * 16 + l15) * 72 +
                                    ks * 32 + l4 * 8];
#pragma unroll
      for (int rt = 0; rt < 4; ++rt) {
        f16x8 a = *(const f16x8*)&Pt[(rt * 16 + l15) * 72 + ks * 32 + l4 * 8];
#pragma unroll
        for (int ct = 0; ct < 4; ++ct)
          acc[rt][ct] = __builtin_amdgcn_mfma_f32_16x16x32_f16(a, bf[ct], acc[rt][ct], 0, 0, 0);
      }
    }
  }
  // ---- epilogue: out[qi] = sum_g wts[qi][g] * acc_g ----
  __syncthreads();
  if (g < 2) {
#pragma unroll
    for (int rt = 0; rt < 4; ++rt)
#pragma unroll
      for (int ct = 0; ct < 4; ++ct)
#pragma unroll
        for (int r = 0; r < 4; ++r)
          Ag[g * 8192 + (rt * 16 + l4 * 4 + r) * 128 + dh * 64 + ct * 16 + l15] =
              acc[rt][ct][r];
  }
  __syncthreads();
  float part[4][16];
#pragma unroll
  for (int i = 0; i < 16; ++i) {
    int e = i * 512 + t;
    int r = e >> 7, c = e & 127;
    float a0 = Ag[r * 128 + c], a1 = Ag[8192 + r * 128 + c];
#pragma unroll
    for (int qi = 0; qi < 4; ++qi)
      part[qi][i] = wts_t[qi * 4 + 0] * a0 + wts_t[qi * 4 + 1] * a1;
  }
  __syncthreads();
  if (g >= 2) {
#pragma unroll
    for (int rt = 0; rt < 4; ++rt)
#pragma unroll
      for (int ct = 0; ct < 4; ++ct)
#pragma unroll
        for (int r = 0; r < 4; ++r)
          Ag[(g - 2) * 8192 + (rt * 16 + l4 * 4 + r) * 128 + dh * 64 + ct * 16 + l15] =
              acc[rt][ct][r];
  }
  __syncthreads();
  float* obase = out + ((size_t)bh * 4096 + q0) * 128;
#pragma unroll
  for (int i = 0; i < 16; ++i) {
    int e = i * 512 + t;
    int r = e >> 7, c = e & 127;
    float a2 = Ag[r * 128 + c], a3 = Ag[8192 + r * 128 + c];
#pragma unroll
    for (int qi = 0; qi < 4; ++qi) {
      float val = part[qi][i] + wts_t[qi * 4 + 2] * a2 + wts_t[qi * 4 + 3] * a3;
      obase[(size_t)(qi * 1024 + r) * 128 + c] = val;
    }
  }
  if (t < 256) {
    int qi = t >> 6, r = t & 63;
    out[16777216 + (size_t)bh * 4096 + qi * 1024 + q0 + r] = lse_t[r] + logSg[bh * 4 + qi];
  }
}

// ---------------- launcher ---------------------------------------------------
#define VT_OFF   0u
#define LSE0_OFF 33554432u
#define N2_OFF   33685504u
#define WTS_OFF  33687552u
#define LOGS_OFF 33689600u
#define KC_OFF   33690112u
#define WS_NEED  42078720u

extern "C" void kernel_launch(void* const* d_in, const int* in_sizes, int n_in,
                              void* d_out, int out_size, void* d_ws, size_t ws_size,
                              hipStream_t stream) {
  const float* q = (const float*)d_in[0];
  const float* k = (const float*)d_in[1];
  const float* v = (const float*)d_in[2];
  float* out = (float*)d_out;
  char* ws = (char*)d_ws;
  if (ws_size < WS_NEED) return;  // diagnosable: dur ~0, absmax = max|ref|

  _Float16* VT   = (_Float16*)(ws + VT_OFF);
  float* lse0    = (float*)(ws + LSE0_OFF);
  float* norms2  = (float*)(ws + N2_OFF);
  float* wtsb    = (float*)(ws + WTS_OFF);
  float* logSb   = (float*)(ws + LOGS_OFF);
  _Float16* Kc   = (_Float16*)(ws + KC_OFF);

  hipFuncSetAttribute(reinterpret_cast<const void*>(k_main),
                      hipFuncAttributeMaxDynamicSharedMemorySize, SMEM_MAIN);

  hipMemsetAsync(norms2, 0, 2048, stream);
  k_build_kc<<<4096, 256, 0, stream>>>(k, Kc);
  k_build_vt<<<1024, 256, 0, stream>>>(v, VT);
  k_norms<<<512, 256, 0, stream>>>(q, k, norms2);
  k_wts<<<1, 128, 0, stream>>>(norms2, wtsb, logSb);
  k_lse0<<<256, 512, 0, stream>>>(q, Kc, lse0);
  k_main<<<512, 512, SMEM_MAIN, stream>>>(q, Kc, VT, lse0, wtsb, logSb, out);
}